// Round 1
// baseline (392.745 us; speedup 1.0000x reference)
//
#include <hip/hip_runtime.h>

#define N_IN   16384
#define N_OUT  16384
#define NE     300000
#define NB     8
#define NCIN   16
#define NCOUT  16
#define SEG_G  4   // segments per block in gather kernel

// ---------------------------------------------------------------------------
// Kernel A: transpose features (128, N_IN) -> ft[N_IN][128]
// ---------------------------------------------------------------------------
__global__ void k_transpose(const float* __restrict__ feat, float* __restrict__ ft) {
    __shared__ float tile[32][33];
    int n0 = blockIdx.x * 32, c0 = blockIdx.y * 32;
    int tx = threadIdx.x, ty = threadIdx.y;
#pragma unroll
    for (int k = 0; k < 4; ++k) {
        int c = c0 + ty + k * 8;
        tile[ty + k * 8][tx] = feat[(size_t)c * N_IN + n0 + tx];
    }
    __syncthreads();
#pragma unroll
    for (int k = 0; k < 4; ++k) {
        int n = n0 + ty + k * 8;
        ft[(size_t)n * 128 + c0 + tx] = tile[tx][ty + k * 8];
    }
}

// ---------------------------------------------------------------------------
// Kernel B: per-edge MLP -> hbuf[e][16] = w_e * sin^5(...) (pre-W5 hidden)
// ---------------------------------------------------------------------------
__global__ void k_mlp(const float* __restrict__ pin, const float* __restrict__ pout,
                      const float* __restrict__ wts, const int2* __restrict__ ei,
                      const float* __restrict__ W0, const float* __restrict__ W1,
                      const float* __restrict__ W2, const float* __restrict__ W3,
                      const float* __restrict__ W4, float* __restrict__ hbuf) {
    __shared__ float w0t[32];       // transposed: w0t[j*2 + i] = W0[i*16 + j]
    __shared__ float wt[4][256];    // transposed: wt[L][j*16 + i] = WL[i*16 + j]
    int tid = threadIdx.x;
    {
        int i = tid >> 4, j = tid & 15;
        if (tid < 32) w0t[j * 2 + (tid >> 4)] = W0[tid];
        wt[0][j * 16 + i] = W1[tid];
        wt[1][j * 16 + i] = W2[tid];
        wt[2][j * 16 + i] = W3[tid];
        wt[3][j * 16 + i] = W4[tid];
    }
    __syncthreads();
    int e = blockIdx.x * 256 + tid;
    if (e >= NE) return;

    int2 oi = ei[e];
    float2 po = ((const float2*)pout)[oi.x];
    float2 pi = ((const float2*)pin)[oi.y];
    float x = po.x - pi.x, y = po.y - pi.y;

    float h[16];
#pragma unroll
    for (int j = 0; j < 16; ++j)
        h[j] = __sinf(x * w0t[j * 2] + y * w0t[j * 2 + 1]);

#pragma unroll
    for (int L = 0; L < 4; ++L) {
        float nh[16];
#pragma unroll
        for (int j = 0; j < 16; ++j) {
            const float4* wr = (const float4*)&wt[L][j * 16];
            float4 a0 = wr[0], a1 = wr[1], a2 = wr[2], a3 = wr[3];
            float w16[16] = {a0.x, a0.y, a0.z, a0.w, a1.x, a1.y, a1.z, a1.w,
                             a2.x, a2.y, a2.z, a2.w, a3.x, a3.y, a3.z, a3.w};
            float acc = 0.f;
#pragma unroll
            for (int i = 0; i < 16; ++i) acc += h[i] * w16[i];
            nh[j] = __sinf(acc);
        }
#pragma unroll
        for (int j = 0; j < 16; ++j) h[j] = nh[j];
    }

    float we = wts[oi.y];
    float4* hb = (float4*)&hbuf[(size_t)e * 16];
    hb[0] = make_float4(we * h[0],  we * h[1],  we * h[2],  we * h[3]);
    hb[1] = make_float4(we * h[4],  we * h[5],  we * h[6],  we * h[7]);
    hb[2] = make_float4(we * h[8],  we * h[9],  we * h[10], we * h[11]);
    hb[3] = make_float4(we * h[12], we * h[13], we * h[14], we * h[15]);
}

// ---------------------------------------------------------------------------
// Kernel C: segment gather + S-accumulate + W5 projection + butterfly reduce
// block = 128 threads: thread t -> (b = t>>4, j = t&15). SEG_G segments/block.
// ---------------------------------------------------------------------------
__global__ void k_gather(const int2* __restrict__ ei, const float* __restrict__ ft,
                         const float* __restrict__ hbuf, const float* __restrict__ W5,
                         float* __restrict__ out) {
    // W5 in LDS with per-row chunk rotation: row r's logical float4-chunk l is
    // stored at physical chunk (l+r)&63 -> reads by 16 j-lanes hit 8 distinct
    // bank-groups (2-way aliasing = free) instead of 16-way conflicts.
    __shared__ float w5l[4096];
    int tid = threadIdx.x;
    int b = tid >> 4, j = tid & 15;
#pragma unroll
    for (int I = tid; I < 4096; I += 128) {
        int r = I >> 8, c = I & 255;
        int l = c >> 2, d = c & 3;
        int phys = (l + r) & 63;
        w5l[r * 256 + phys * 4 + d] = W5[I];
    }
    __syncthreads();

    int n0 = blockIdx.x * SEG_G;
    // binary search: first edge with idx_out >= n0, and >= n0+SEG_G
    int lo = 0, hi = NE;
    while (lo < hi) { int m = (lo + hi) >> 1; if (ei[m].x < n0) lo = m + 1; else hi = m; }
    int e = lo;
    lo = e; hi = NE;
    while (lo < hi) { int m = (lo + hi) >> 1; if (ei[m].x < n0 + SEG_G) lo = m + 1; else hi = m; }
    int eend = lo;

    for (int n = n0; n < n0 + SEG_G; ++n) {
        float S[16];
#pragma unroll
        for (int i = 0; i < 16; ++i) S[i] = 0.f;

        while (e < eend) {
            int2 oi = ei[e];
            if (oi.x != n) break;
            float hv = hbuf[(size_t)e * 16 + j];              // w_e * h_e[j]
            const float4* fp = (const float4*)&ft[(size_t)oi.y * 128 + b * 16];
            float4 f0 = fp[0], f1 = fp[1], f2 = fp[2], f3 = fp[3];
            float fv[16] = {f0.x, f0.y, f0.z, f0.w, f1.x, f1.y, f1.z, f1.w,
                            f2.x, f2.y, f2.z, f2.w, f3.x, f3.y, f3.z, f3.w};
#pragma unroll
            for (int i = 0; i < 16; ++i) S[i] += hv * fv[i];
            ++e;
        }

        // finalize: p[o] = sum_i S[i] * W5[j][16i + o]
        float p[16];
#pragma unroll
        for (int o = 0; o < 16; ++o) p[o] = 0.f;
#pragma unroll
        for (int l = 0; l < 64; ++l) {
            int i = l >> 2, d = l & 3;
            int phys = (l + j) & 63;
            const float4 w = *(const float4*)&w5l[j * 256 + phys * 4];
            p[4 * d + 0] += S[i] * w.x;
            p[4 * d + 1] += S[i] * w.y;
            p[4 * d + 2] += S[i] * w.z;
            p[4 * d + 3] += S[i] * w.w;
        }

        // halving butterfly over the 16 j-lanes; lane j ends with out[b][o=j]
        float q8[8];
#pragma unroll
        for (int u = 0; u < 8; ++u) {
            float a = p[2 * u], bb = p[2 * u + 1];
            float keep = (j & 1) ? bb : a;
            float send = (j & 1) ? a : bb;
            q8[u] = keep + __shfl_xor(send, 1);
        }
        float q4[4];
#pragma unroll
        for (int u = 0; u < 4; ++u) {
            float a = q8[2 * u], bb = q8[2 * u + 1];
            float keep = (j & 2) ? bb : a;
            float send = (j & 2) ? a : bb;
            q4[u] = keep + __shfl_xor(send, 2);
        }
        float q2[2];
#pragma unroll
        for (int u = 0; u < 2; ++u) {
            float a = q4[2 * u], bb = q4[2 * u + 1];
            float keep = (j & 4) ? bb : a;
            float send = (j & 4) ? a : bb;
            q2[u] = keep + __shfl_xor(send, 4);
        }
        float a = q2[0], bb = q2[1];
        float keep = (j & 8) ? bb : a;
        float send = (j & 8) ? a : bb;
        float q1 = keep + __shfl_xor(send, 8);

        out[(size_t)(b * 16 + j) * N_OUT + n] = q1;
    }
}

// ---------------------------------------------------------------------------
extern "C" void kernel_launch(void* const* d_in, const int* in_sizes, int n_in,
                              void* d_out, int out_size, void* d_ws, size_t ws_size,
                              hipStream_t stream) {
    const float* pin  = (const float*)d_in[0];
    const float* pout = (const float*)d_in[1];
    const float* wts  = (const float*)d_in[2];
    const float* feat = (const float*)d_in[3];
    const int2*  ei   = (const int2*)d_in[4];
    const float* W0   = (const float*)d_in[5];
    const float* W1   = (const float*)d_in[6];
    const float* W2   = (const float*)d_in[7];
    const float* W3   = (const float*)d_in[8];
    const float* W4   = (const float*)d_in[9];
    const float* W5   = (const float*)d_in[10];
    float* out = (float*)d_out;

    float* ft   = (float*)d_ws;                       // 16384*128*4 = 8 MB
    float* hbuf = ft + (size_t)N_IN * 128;            // 300000*16*4 = 19.2 MB

    k_transpose<<<dim3(N_IN / 32, 4), dim3(32, 8), 0, stream>>>(feat, ft);
    k_mlp<<<(NE + 255) / 256, 256, 0, stream>>>(pin, pout, wts, ei,
                                                W0, W1, W2, W3, W4, hbuf);
    k_gather<<<N_OUT / SEG_G, 128, 0, stream>>>(ei, ft, hbuf, W5, out);
}

// Round 2
// 123.039 us; speedup vs baseline: 3.1920x; 3.1920x over previous
//
#include <hip/hip_runtime.h>

#define N_IN   16384
#define N_OUT  16384
#define NE     300000

typedef unsigned int   u32;
typedef unsigned short u16;

// round-to-nearest-even fp32 -> bf16 bits
__device__ __forceinline__ u16 f2bf(float x) {
    union { float f; u32 u; } v; v.f = x;
    u32 r = v.u + 0x7fffu + ((v.u >> 16) & 1u);
    return (u16)(r >> 16);
}

// ---------------------------------------------------------------------------
// Kernel A: transpose features (128, N_IN) fp32 -> ftb[N_IN][128] bf16
// ---------------------------------------------------------------------------
__global__ void k_transpose(const float* __restrict__ feat, u16* __restrict__ ftb) {
    __shared__ float tile[32][33];
    int n0 = blockIdx.x * 32, c0 = blockIdx.y * 32;
    int tx = threadIdx.x, ty = threadIdx.y;
#pragma unroll
    for (int k = 0; k < 4; ++k)
        tile[ty + k * 8][tx] = feat[(size_t)(c0 + ty + k * 8) * N_IN + n0 + tx];
    __syncthreads();
#pragma unroll
    for (int k = 0; k < 4; ++k)
        ftb[(size_t)(n0 + ty + k * 8) * 128 + c0 + tx] = f2bf(tile[tx][ty + k * 8]);
}

// ---------------------------------------------------------------------------
// Kernel B: segment offsets via parallel binary search over sorted idx_out
// ---------------------------------------------------------------------------
__global__ void k_segoff(const int2* __restrict__ ei, int* __restrict__ segoff) {
    int n = blockIdx.x * 256 + threadIdx.x;
    if (n > N_OUT) return;
    if (n == N_OUT) { segoff[n] = NE; return; }
    int lo = 0, hi = NE;
    while (lo < hi) { int m = (lo + hi) >> 1; if (ei[m].x < n) lo = m + 1; else hi = m; }
    segoff[n] = lo;
}

// ---------------------------------------------------------------------------
// Kernel C: per-edge MLP -> hbuf[e][16] = bf16( w_e * sin^5(...) )
// ---------------------------------------------------------------------------
__global__ void k_mlp(const float* __restrict__ pin, const float* __restrict__ pout,
                      const float* __restrict__ wts, const int2* __restrict__ ei,
                      const float* __restrict__ W0, const float* __restrict__ W1,
                      const float* __restrict__ W2, const float* __restrict__ W3,
                      const float* __restrict__ W4, u16* __restrict__ hbuf) {
    __shared__ float w0t[32];
    __shared__ float wt[4][256];
    int tid = threadIdx.x;
    {
        int i = tid >> 4, j = tid & 15;
        if (tid < 32) w0t[(tid & 15) * 2 + (tid >> 4)] = W0[tid];
        wt[0][j * 16 + i] = W1[tid];
        wt[1][j * 16 + i] = W2[tid];
        wt[2][j * 16 + i] = W3[tid];
        wt[3][j * 16 + i] = W4[tid];
    }
    __syncthreads();
    int e = blockIdx.x * 256 + tid;
    if (e >= NE) return;

    int2 oi = ei[e];
    float2 po = ((const float2*)pout)[oi.x];
    float2 pi = ((const float2*)pin)[oi.y];
    float x = po.x - pi.x, y = po.y - pi.y;

    float h[16];
#pragma unroll
    for (int j = 0; j < 16; ++j)
        h[j] = __sinf(x * w0t[j * 2] + y * w0t[j * 2 + 1]);

#pragma unroll
    for (int L = 0; L < 4; ++L) {
        float nh[16];
#pragma unroll
        for (int j = 0; j < 16; ++j) {
            const float4* wr = (const float4*)&wt[L][j * 16];
            float4 a0 = wr[0], a1 = wr[1], a2 = wr[2], a3 = wr[3];
            float w16[16] = {a0.x, a0.y, a0.z, a0.w, a1.x, a1.y, a1.z, a1.w,
                             a2.x, a2.y, a2.z, a2.w, a3.x, a3.y, a3.z, a3.w};
            float acc = 0.f;
#pragma unroll
            for (int i = 0; i < 16; ++i) acc += h[i] * w16[i];
            nh[j] = __sinf(acc);
        }
#pragma unroll
        for (int j = 0; j < 16; ++j) h[j] = nh[j];
    }

    float we = wts[oi.y];
    u16 hs[16];
#pragma unroll
    for (int j = 0; j < 16; ++j) hs[j] = f2bf(we * h[j]);
    uint4 u0, u1;
    u0.x = (u32)hs[0]  | ((u32)hs[1]  << 16);
    u0.y = (u32)hs[2]  | ((u32)hs[3]  << 16);
    u0.z = (u32)hs[4]  | ((u32)hs[5]  << 16);
    u0.w = (u32)hs[6]  | ((u32)hs[7]  << 16);
    u1.x = (u32)hs[8]  | ((u32)hs[9]  << 16);
    u1.y = (u32)hs[10] | ((u32)hs[11] << 16);
    u1.z = (u32)hs[12] | ((u32)hs[13] << 16);
    u1.w = (u32)hs[14] | ((u32)hs[15] << 16);
    uint4* hp = (uint4*)(hbuf + (size_t)e * 16);
    hp[0] = u0; hp[1] = u1;
}

// ---------------------------------------------------------------------------
// Kernel D: one block (128 thr) per segment. thread t -> (b=t>>4, j=t&15).
// Cooperative ei chunk load + shfl broadcast; depth-2 pipelined bf16 gather;
// W5 projection from rotated LDS; butterfly over j; coalesced outT write.
// ---------------------------------------------------------------------------
#define ACC8(S, off, v, hv)                                              \
    do {                                                                 \
        S[(off) + 0] += (hv) * __uint_as_float((v).x << 16);             \
        S[(off) + 1] += (hv) * __uint_as_float((v).x & 0xffff0000u);     \
        S[(off) + 2] += (hv) * __uint_as_float((v).y << 16);             \
        S[(off) + 3] += (hv) * __uint_as_float((v).y & 0xffff0000u);     \
        S[(off) + 4] += (hv) * __uint_as_float((v).z << 16);             \
        S[(off) + 5] += (hv) * __uint_as_float((v).z & 0xffff0000u);     \
        S[(off) + 6] += (hv) * __uint_as_float((v).w << 16);             \
        S[(off) + 7] += (hv) * __uint_as_float((v).w & 0xffff0000u);     \
    } while (0)

__global__ __launch_bounds__(128) void k_gather(
        const int2* __restrict__ ei, const u16* __restrict__ ftb,
        const u16* __restrict__ hb, const float* __restrict__ W5,
        const int* __restrict__ segoff, float* __restrict__ outT) {
    __shared__ float w5l[4096];
    int tid = threadIdx.x;
    int b = tid >> 4, j = tid & 15, lane = tid & 63;
    // stage W5 with per-row chunk rotation (row r chunk l -> phys (l+r)&63)
#pragma unroll
    for (int I = tid; I < 4096; I += 128) {
        int r = I >> 8, c = I & 255;
        int l = c >> 2, d = c & 3;
        int phys = (l + r) & 63;
        w5l[r * 256 + phys * 4 + d] = W5[I];
    }

    int n = blockIdx.x;
    int e0 = segoff[n], e1 = segoff[n + 1];

    float S[16];
#pragma unroll
    for (int i = 0; i < 16; ++i) S[i] = 0.f;

    for (int base = e0; base < e1; base += 64) {
        int cnt = min(64, e1 - base);
        int myi = 0;
        if (base + lane < e1) myi = ei[base + lane].y;

        // depth-2 software pipeline
        uint4 a0, a1; u32 ha;
        {
            int idx = __shfl(myi, 0);
            const uint4* fp = (const uint4*)(ftb + ((size_t)idx << 7) + (b << 4));
            a0 = fp[0]; a1 = fp[1];
            ha = hb[((size_t)base << 4) + j];
        }
        for (int i = 0; i + 1 < cnt; ++i) {
            uint4 c0, c1; u32 hc;
            {
                int idx = __shfl(myi, i + 1);
                const uint4* fp = (const uint4*)(ftb + ((size_t)idx << 7) + (b << 4));
                c0 = fp[0]; c1 = fp[1];
                hc = hb[((size_t)(base + i + 1) << 4) + j];
            }
            float hv = __uint_as_float(ha << 16);
            ACC8(S, 0, a0, hv);
            ACC8(S, 8, a1, hv);
            a0 = c0; a1 = c1; ha = hc;
        }
        float hv = __uint_as_float(ha << 16);
        ACC8(S, 0, a0, hv);
        ACC8(S, 8, a1, hv);
    }

    __syncthreads();   // w5l ready

    // p[o] = sum_i S[i] * W5[j][16i+o]
    float p[16];
#pragma unroll
    for (int o = 0; o < 16; ++o) p[o] = 0.f;
#pragma unroll
    for (int l = 0; l < 64; ++l) {
        int i = l >> 2, d = l & 3;
        int phys = (l + j) & 63;
        const float4 w = *(const float4*)&w5l[j * 256 + phys * 4];
        p[4 * d + 0] += S[i] * w.x;
        p[4 * d + 1] += S[i] * w.y;
        p[4 * d + 2] += S[i] * w.z;
        p[4 * d + 3] += S[i] * w.w;
    }

    // halving butterfly over the 16 j-lanes; lane j ends with out[b][o=j]
    float q8[8];
#pragma unroll
    for (int u = 0; u < 8; ++u) {
        float a = p[2 * u], bb = p[2 * u + 1];
        float keep = (j & 1) ? bb : a;
        float send = (j & 1) ? a : bb;
        q8[u] = keep + __shfl_xor(send, 1);
    }
    float q4[4];
#pragma unroll
    for (int u = 0; u < 4; ++u) {
        float a = q8[2 * u], bb = q8[2 * u + 1];
        float keep = (j & 2) ? bb : a;
        float send = (j & 2) ? a : bb;
        q4[u] = keep + __shfl_xor(send, 2);
    }
    float q2[2];
#pragma unroll
    for (int u = 0; u < 2; ++u) {
        float a = q4[2 * u], bb = q4[2 * u + 1];
        float keep = (j & 4) ? bb : a;
        float send = (j & 4) ? a : bb;
        q2[u] = keep + __shfl_xor(send, 4);
    }
    float a = q2[0], bb = q2[1];
    float keep = (j & 8) ? bb : a;
    float send = (j & 8) ? a : bb;
    float q1 = keep + __shfl_xor(send, 8);

    outT[(size_t)n * 128 + tid] = q1;   // coalesced 512B per block
}

// ---------------------------------------------------------------------------
// Kernel E: transpose outT[N_OUT][128] -> out[128][N_OUT]
// ---------------------------------------------------------------------------
__global__ void k_outfinal(const float* __restrict__ outT, float* __restrict__ out) {
    __shared__ float tile[32][33];
    int n0 = blockIdx.x * 32, k0 = blockIdx.y * 32;
    int tx = threadIdx.x, ty = threadIdx.y;
#pragma unroll
    for (int k = 0; k < 4; ++k)
        tile[ty + k * 8][tx] = outT[(size_t)(n0 + ty + k * 8) * 128 + k0 + tx];
    __syncthreads();
#pragma unroll
    for (int k = 0; k < 4; ++k)
        out[(size_t)(k0 + ty + k * 8) * N_OUT + n0 + tx] = tile[tx][ty + k * 8];
}

// ---------------------------------------------------------------------------
extern "C" void kernel_launch(void* const* d_in, const int* in_sizes, int n_in,
                              void* d_out, int out_size, void* d_ws, size_t ws_size,
                              hipStream_t stream) {
    const float* pin  = (const float*)d_in[0];
    const float* pout = (const float*)d_in[1];
    const float* wts  = (const float*)d_in[2];
    const float* feat = (const float*)d_in[3];
    const int2*  ei   = (const int2*)d_in[4];
    const float* W0   = (const float*)d_in[5];
    const float* W1   = (const float*)d_in[6];
    const float* W2   = (const float*)d_in[7];
    const float* W3   = (const float*)d_in[8];
    const float* W4   = (const float*)d_in[9];
    const float* W5   = (const float*)d_in[10];
    float* out = (float*)d_out;

    u16*   ftb    = (u16*)d_ws;                         //  4 MB
    u16*   hbuf   = ftb + (size_t)N_IN * 128;           //  9.6 MB
    float* outT   = (float*)(hbuf + (size_t)NE * 16);   //  8 MB
    int*   segoff = (int*)(outT + (size_t)N_OUT * 128); // 64 KB

    k_transpose<<<dim3(N_IN / 32, 4), dim3(32, 8), 0, stream>>>(feat, ftb);
    k_segoff<<<(N_OUT + 256) / 256, 256, 0, stream>>>(ei, segoff);
    k_mlp<<<(NE + 255) / 256, 256, 0, stream>>>(pin, pout, wts, ei,
                                                W0, W1, W2, W3, W4, hbuf);
    k_gather<<<N_OUT, 128, 0, stream>>>(ei, ftb, hbuf, W5, segoff, outT);
    k_outfinal<<<dim3(N_OUT / 32, 4), dim3(32, 8), 0, stream>>>(outT, out);
}